// Round 1
// baseline (89.485 us; speedup 1.0000x reference)
//
#include <hip/hip_runtime.h>
#include <hip/hip_bf16.h>

typedef unsigned int u32;
typedef unsigned short u16;
typedef __bf16 bf16x8 __attribute__((ext_vector_type(8)));
typedef float f32x4 __attribute__((ext_vector_type(4)));

#define N_SPATIAL 4096
#define K_SEL 409
#define NBATCH 32
#define NCHAN 256

__device__ __forceinline__ u16 f2bf(float f) {
    __hip_bfloat16 h = __float2bfloat16(f);
    return *reinterpret_cast<u16*>(&h);
}

__device__ __forceinline__ void gload_lds16(const void* g, void* l) {
    __builtin_amdgcn_global_load_lds((const __attribute__((address_space(1))) void*)g,
                                     (__attribute__((address_space(3))) void*)l, 16, 0, 0);
}

// ---------------- Kernel A: per-row exact top-k threshold + sparsify to bf16 ----------------
// One block per (b,c) row of 4096 elements. 3-pass radix select (11/11/10 bits) on abs-bits.
__global__ __launch_bounds__(256) void topk_sparsify(const float* __restrict__ x,
                                                     u16* __restrict__ Fout) {
    __shared__ u32 hist[2048];
    __shared__ u32 waveSum[4];
    __shared__ u32 sh_pref, sh_krem;

    const int t = threadIdx.x;
    const int lane = t & 63;
    const int wid = t >> 6;
    const int row = blockIdx.x;
    const float* xr = x + (size_t)row * N_SPATIAL;

    // load 16 floats/thread, coalesced float4
    float4 v[4];
#pragma unroll
    for (int j = 0; j < 4; ++j)
        v[j] = reinterpret_cast<const float4*>(xr)[t + 256 * j];

    u32 pref = 0, krem = K_SEL;
    const int shifts[3] = {21, 10, 0};
    const int nbits[3]  = {11, 11, 10};

#pragma unroll
    for (int p = 0; p < 3; ++p) {
        const int shift = shifts[p];
        const int bins = 1 << nbits[p];
        const int mshift = (p == 0) ? 31 : shifts[p - 1];

        for (int i = t; i < bins; i += 256) hist[i] = 0;
        __syncthreads();

#pragma unroll
        for (int j = 0; j < 4; ++j) {
            const float* vf = reinterpret_cast<const float*>(&v[j]);
#pragma unroll
            for (int e = 0; e < 4; ++e) {
                u32 key = __float_as_uint(vf[e]) & 0x7fffffffu;
                if (p == 0 || ((key >> mshift) == pref))
                    atomicAdd(&hist[(key >> shift) & (bins - 1)], 1u);
            }
        }
        __syncthreads();

        // suffix-count scan: chunk per thread
        const int bpt = bins / 256;       // 8,8,4
        const int base = t * bpt;
        u32 hloc[8];
        u32 csum = 0;
#pragma unroll
        for (int j = 0; j < 8; ++j) {
            if (j < bpt) { hloc[j] = hist[base + j]; csum += hloc[j]; }
        }
        // wave-level inclusive suffix sum over chunk sums
        u32 s = csum;
#pragma unroll
        for (int d = 1; d < 64; d <<= 1) {
            u32 o = __shfl_down(s, d);
            if (lane + d < 64) s += o;
        }
        if (lane == 0) waveSum[wid] = s;
        __syncthreads();
        u32 above = s - csum;             // chunks above within wave
        for (int w2 = wid + 1; w2 < 4; ++w2) above += waveSum[w2];

        // walk own bins high->low; exactly one (thread,bin) crosses krem
        u32 cum = above;
#pragma unroll
        for (int j = 7; j >= 0; --j) {
            if (j < bpt) {
                u32 c = hloc[j];
                if (cum < krem && cum + c >= krem) {
                    sh_pref = (pref << nbits[p]) | (u32)(base + j);
                    sh_krem = krem - cum;
                }
                cum += c;
            }
        }
        __syncthreads();
        pref = sh_pref;
        krem = sh_krem;
        __syncthreads();
    }

    const u32 thr = pref;   // abs-bits of k-th largest
    const size_t obase = (size_t)row * N_SPATIAL;
#pragma unroll
    for (int j = 0; j < 4; ++j) {
        const float* vf = reinterpret_cast<const float*>(&v[j]);
        ushort4 o;
        u16* op = reinterpret_cast<u16*>(&o);
#pragma unroll
        for (int e = 0; e < 4; ++e) {
            u32 key = __float_as_uint(vf[e]) & 0x7fffffffu;
            float f = (key >= thr) ? vf[e] : 0.0f;
            op[e] = f2bf(f);
        }
        *reinterpret_cast<ushort4*>(Fout + obase + 4 * t + 1024 * j) = o;
    }
}

// ---------------- Kernel B: batched G = F F^T tile + fused loss partial ----------------
// 512 blocks: 32 batches x (4x4 tiles of 64x64). 256 threads = 4 waves, each 32x32.
__global__ __launch_bounds__(256) void gram_loss(const u16* __restrict__ F,
                                                 const float* __restrict__ T,
                                                 float* __restrict__ partials) {
    __shared__ __align__(16) u16 As[64 * 64];
    __shared__ __align__(16) u16 Bs[64 * 64];
    __shared__ float red[4];

    const int t = threadIdx.x;
    const int lane = t & 63;
    const int wid = t >> 6;

    // XCD grouping: batch b lands on xcd b%8; batches time-grouped in dispatch order
    const int d = blockIdx.x;
    const int xcd = d & 7;
    const int within = d >> 3;
    const int grp = within >> 4;      // 0..3
    const int sub = within & 15;      // 0..15
    const int b = xcd + 8 * grp;
    const int ti = sub >> 2, tj = sub & 3;
    const int i0 = ti * 64, j0 = tj * 64;

    const u16* Fb = F + (size_t)b * NCHAN * N_SPATIAL;
    const int wr = wid >> 1, wc = wid & 1;

    // staging geometry (per q issue): chunk c = q*256+t; row=c>>3; c16=c&7; src chunk = c16 ^ (row&7)
    const int c0 = t, c1 = 256 + t;
    const int r0 = c0 >> 3, s0 = (c0 & 7) ^ (r0 & 7);
    const int r1 = c1 >> 3, s1 = (c1 & 7) ^ (r1 & 7);
    const u16* gA0 = Fb + (size_t)(i0 + r0) * N_SPATIAL + s0 * 8;
    const u16* gA1 = Fb + (size_t)(i0 + r1) * N_SPATIAL + s1 * 8;
    const u16* gB0 = Fb + (size_t)(j0 + r0) * N_SPATIAL + s0 * 8;
    const u16* gB1 = Fb + (size_t)(j0 + r1) * N_SPATIAL + s1 * 8;

    f32x4 acc[2][2] = {};

    for (int kk = 0; kk < 64; ++kk) {
        const int kb = kk * 64;
        gload_lds16(gA0 + kb, As + c0 * 8);
        gload_lds16(gA1 + kb, As + c1 * 8);
        gload_lds16(gB0 + kb, Bs + c0 * 8);
        gload_lds16(gB1 + kb, Bs + c1 * 8);
        __syncthreads();   // compiler emits vmcnt(0) drain before barrier

#pragma unroll
        for (int ks = 0; ks < 2; ++ks) {
            const int kc0 = ks * 4 + (lane >> 4);   // 16B chunk index within row
            bf16x8 a[2], bb[2];
#pragma unroll
            for (int m = 0; m < 2; ++m) {
                int r = wr * 32 + m * 16 + (lane & 15);
                a[m] = *reinterpret_cast<const bf16x8*>(As + r * 64 + ((kc0 ^ (r & 7)) * 8));
            }
#pragma unroll
            for (int n = 0; n < 2; ++n) {
                int r = wc * 32 + n * 16 + (lane & 15);
                bb[n] = *reinterpret_cast<const bf16x8*>(Bs + r * 64 + ((kc0 ^ (r & 7)) * 8));
            }
#pragma unroll
            for (int m = 0; m < 2; ++m)
#pragma unroll
                for (int n = 0; n < 2; ++n)
                    acc[m][n] = __builtin_amdgcn_mfma_f32_16x16x32_bf16(a[m], bb[n], acc[m][n], 0, 0, 0);
        }
        __syncthreads();
    }

    // fused loss epilogue: G = acc/33554432 ; sum (T-G)^2 over this 64x64 tile
    const float invNorm = 1.0f / 33554432.0f;
    const float* Tb = T + (size_t)b * (NCHAN * NCHAN);
    float s = 0.f;
#pragma unroll
    for (int m = 0; m < 2; ++m)
#pragma unroll
        for (int n = 0; n < 2; ++n) {
            const int col = j0 + wc * 32 + n * 16 + (lane & 15);
#pragma unroll
            for (int r = 0; r < 4; ++r) {
                const int rowi = i0 + wr * 32 + m * 16 + (lane >> 4) * 4 + r;
                float g = acc[m][n][r] * invNorm;
                float diff = Tb[rowi * NCHAN + col] - g;
                s += diff * diff;
            }
        }
#pragma unroll
    for (int dd = 32; dd >= 1; dd >>= 1) s += __shfl_down(s, dd);
    if (lane == 0) red[wid] = s;
    __syncthreads();
    if (t == 0) partials[d] = red[0] + red[1] + red[2] + red[3];
}

// ---------------- Kernel C: deterministic final reduction ----------------
__global__ __launch_bounds__(256) void final_reduce(const float* __restrict__ partials,
                                                    float* __restrict__ out) {
    __shared__ float red[4];
    const int t = threadIdx.x;
    const int lane = t & 63;
    const int wid = t >> 6;
    float s = partials[t] + partials[t + 256];
#pragma unroll
    for (int dd = 32; dd >= 1; dd >>= 1) s += __shfl_down(s, dd);
    if (lane == 0) red[wid] = s;
    __syncthreads();
    if (t == 0) out[0] = (red[0] + red[1] + red[2] + red[3]) * (1.0e9f / 2097152.0f);
}

extern "C" void kernel_launch(void* const* d_in, const int* in_sizes, int n_in,
                              void* d_out, int out_size, void* d_ws, size_t ws_size,
                              hipStream_t stream) {
    const float* x  = (const float*)d_in[0];           // (32,256,64,64) fp32
    const float* tg = (const float*)d_in[1];           // (32,256,256) fp32
    float* out = (float*)d_out;

    // ws layout: [0,2KiB) partials (512 f32); [4096, 4096+64MiB) F as bf16
    float* partials = (float*)d_ws;
    u16* F = (u16*)((char*)d_ws + 4096);

    topk_sparsify<<<NBATCH * NCHAN, 256, 0, stream>>>(x, F);
    gram_loss<<<512, 256, 0, stream>>>(F, tg, partials);
    final_reduce<<<1, 256, 0, stream>>>(partials, out);
}

// Round 3
// 82.013 us; speedup vs baseline: 1.0911x; 1.0911x over previous
//
#include <hip/hip_runtime.h>
#include <hip/hip_bf16.h>

typedef unsigned int u32;
typedef unsigned short u16;
typedef __bf16 bf16x8 __attribute__((ext_vector_type(8)));
typedef float f32x4 __attribute__((ext_vector_type(4)));

#define N_SPATIAL 4096
#define K_SEL 409
#define NBATCH 32
#define NCHAN 256
#define NTILE 10   // upper-tri 64x64 tiles of 4x4 grid

__constant__ int c_TI[NTILE] = {0,0,0,0,1,1,1,2,2,3};
__constant__ int c_TJ[NTILE] = {0,1,2,3,1,2,3,2,3,3};

__device__ __forceinline__ u16 f2bf(float f) {
    __hip_bfloat16 h = __float2bfloat16(f);
    return *reinterpret_cast<u16*>(&h);
}

__device__ __forceinline__ void gload_lds16(const void* g, void* l) {
    __builtin_amdgcn_global_load_lds((const __attribute__((address_space(1))) void*)g,
                                     (__attribute__((address_space(3))) void*)l, 16, 0, 0);
}

// ---------------- Kernel A: per-row exact top-k threshold + sparsify to bf16 ----------------
__global__ __launch_bounds__(256) void topk_sparsify(const float* __restrict__ x,
                                                     u16* __restrict__ Fout) {
    __shared__ u32 hist[2048];
    __shared__ u32 waveSum[4];
    __shared__ u32 sh_pref, sh_krem;

    const int t = threadIdx.x;
    const int lane = t & 63;
    const int wid = t >> 6;
    const int row = blockIdx.x;
    const float* xr = x + (size_t)row * N_SPATIAL;

    float4 v[4];
#pragma unroll
    for (int j = 0; j < 4; ++j)
        v[j] = reinterpret_cast<const float4*>(xr)[t + 256 * j];

    u32 pref = 0, krem = K_SEL;
    const int shifts[3] = {21, 10, 0};
    const int nbits[3]  = {11, 11, 10};

#pragma unroll
    for (int p = 0; p < 3; ++p) {
        const int shift = shifts[p];
        const int bins = 1 << nbits[p];
        const int mshift = (p == 0) ? 31 : shifts[p - 1];

        for (int i = t; i < bins; i += 256) hist[i] = 0;
        __syncthreads();

#pragma unroll
        for (int j = 0; j < 4; ++j) {
            const float* vf = reinterpret_cast<const float*>(&v[j]);
#pragma unroll
            for (int e = 0; e < 4; ++e) {
                u32 key = __float_as_uint(vf[e]) & 0x7fffffffu;
                if (p == 0 || ((key >> mshift) == pref))
                    atomicAdd(&hist[(key >> shift) & (bins - 1)], 1u);
            }
        }
        __syncthreads();

        const int bpt = bins / 256;
        const int base = t * bpt;
        u32 hloc[8];
        u32 csum = 0;
#pragma unroll
        for (int j = 0; j < 8; ++j) {
            if (j < bpt) { hloc[j] = hist[base + j]; csum += hloc[j]; }
        }
        u32 s = csum;
#pragma unroll
        for (int d = 1; d < 64; d <<= 1) {
            u32 o = __shfl_down(s, d);
            if (lane + d < 64) s += o;
        }
        if (lane == 0) waveSum[wid] = s;
        __syncthreads();
        u32 above = s - csum;
        for (int w2 = wid + 1; w2 < 4; ++w2) above += waveSum[w2];

        u32 cum = above;
#pragma unroll
        for (int j = 7; j >= 0; --j) {
            if (j < bpt) {
                u32 c = hloc[j];
                if (cum < krem && cum + c >= krem) {
                    sh_pref = (pref << nbits[p]) | (u32)(base + j);
                    sh_krem = krem - cum;
                }
                cum += c;
            }
        }
        __syncthreads();
        pref = sh_pref;
        krem = sh_krem;
        __syncthreads();
    }

    const u32 thr = pref;
    const size_t obase = (size_t)row * N_SPATIAL;
#pragma unroll
    for (int j = 0; j < 4; ++j) {
        const float* vf = reinterpret_cast<const float*>(&v[j]);
        ushort4 o;
        u16* op = reinterpret_cast<u16*>(&o);
#pragma unroll
        for (int e = 0; e < 4; ++e) {
            u32 key = __float_as_uint(vf[e]) & 0x7fffffffu;
            float f = (key >= thr) ? vf[e] : 0.0f;
            op[e] = f2bf(f);
        }
        *reinterpret_cast<ushort4*>(Fout + obase + 4 * t + 1024 * j) = o;
    }
}

// ---------------- Kernel B: symmetric gram partial, K-split 2, 2-phase pipeline ----------------
// 640 blocks = 32 batches x 10 upper-tri tiles x 2 K-halves. XCD-grouped by batch.
__global__ __launch_bounds__(256) void gram_partial(const u16* __restrict__ F,
                                                    float* __restrict__ pg) {
    __shared__ __align__(16) u16 As[2][64 * 64];
    __shared__ __align__(16) u16 Bs[2][64 * 64];

    const int t = threadIdx.x;
    const int lane = t & 63;
    const int wid = t >> 6;

    // XCD grouping: same-batch blocks share an XCD's L2 (2 MiB F-slice fits)
    const int bid = blockIdx.x;
    const int xcd = bid & 7;
    const int idx = bid >> 3;           // 0..79
    const int b = (idx / 20) * 8 + xcd; // 0..31
    const int sub = idx % 20;
    const int tile = sub >> 1;          // 0..9
    const int half = sub & 1;
    const int ti = c_TI[tile], tj = c_TJ[tile];
    const bool diag = (ti == tj);
    const int i0 = ti * 64, j0 = tj * 64;
    const int kbase = half * 2048;

    const u16* Fb = F + (size_t)b * NCHAN * N_SPATIAL;
    const int wr = wid >> 1, wc = wid & 1;

    // staging geometry: chunk c over 2 issues; row=c>>3; src chunk = (c&7) ^ (row&7)
    const int c0 = t, c1 = 256 + t;
    const int r0 = c0 >> 3, s0 = (c0 & 7) ^ (r0 & 7);
    const int r1 = c1 >> 3, s1 = (c1 & 7) ^ (r1 & 7);
    const u16* gA0 = Fb + (size_t)(i0 + r0) * N_SPATIAL + s0 * 8 + kbase;
    const u16* gA1 = Fb + (size_t)(i0 + r1) * N_SPATIAL + s1 * 8 + kbase;
    const u16* gB0 = Fb + (size_t)(j0 + r0) * N_SPATIAL + s0 * 8 + kbase;
    const u16* gB1 = Fb + (size_t)(j0 + r1) * N_SPATIAL + s1 * 8 + kbase;

    f32x4 acc[2][2] = {};

    const int NKK = 32;  // K=2048 per half, BK=64

    // prologue: stage tile 0 into buf 0
    {
        gload_lds16(gA0, &As[0][c0 * 8]);
        gload_lds16(gA1, &As[0][c1 * 8]);
        if (!diag) {
            gload_lds16(gB0, &Bs[0][c0 * 8]);
            gload_lds16(gB1, &Bs[0][c1 * 8]);
        }
    }
    __syncthreads();

    int cur = 0;
    for (int kk = 0; kk < NKK; ++kk) {
        // issue next tile's loads into the other buffer BEFORE compute (2-phase)
        if (kk + 1 < NKK) {
            const int kb = (kk + 1) * 64;
            gload_lds16(gA0 + kb, &As[cur ^ 1][c0 * 8]);
            gload_lds16(gA1 + kb, &As[cur ^ 1][c1 * 8]);
            if (!diag) {
                gload_lds16(gB0 + kb, &Bs[cur ^ 1][c0 * 8]);
                gload_lds16(gB1 + kb, &Bs[cur ^ 1][c1 * 8]);
            }
        }

        const u16* Ab = &As[cur][0];
        const u16* Bb = diag ? &As[cur][0] : &Bs[cur][0];
#pragma unroll
        for (int ks = 0; ks < 2; ++ks) {
            const int kc0 = ks * 4 + (lane >> 4);
            bf16x8 a[2], bb[2];
#pragma unroll
            for (int m = 0; m < 2; ++m) {
                int r = wr * 32 + m * 16 + (lane & 15);
                a[m] = *reinterpret_cast<const bf16x8*>(Ab + r * 64 + ((kc0 ^ (r & 7)) * 8));
            }
#pragma unroll
            for (int n = 0; n < 2; ++n) {
                int r = wc * 32 + n * 16 + (lane & 15);
                bb[n] = *reinterpret_cast<const bf16x8*>(Bb + r * 64 + ((kc0 ^ (r & 7)) * 8));
            }
#pragma unroll
            for (int m = 0; m < 2; ++m)
#pragma unroll
                for (int n = 0; n < 2; ++n)
                    acc[m][n] = __builtin_amdgcn_mfma_f32_16x16x32_bf16(a[m], bb[n], acc[m][n], 0, 0, 0);
        }
        __syncthreads();   // drains vmcnt(0): next tile staged; all waves done reading cur
        cur ^= 1;
    }

    // write partial G tile (fp32, row-major 64x64) to ws
    float* pt = pg + (size_t)(((b * NTILE + tile) * 2 + half)) * 4096;
#pragma unroll
    for (int m = 0; m < 2; ++m)
#pragma unroll
        for (int n = 0; n < 2; ++n) {
            const int col = wc * 32 + n * 16 + (lane & 15);
#pragma unroll
            for (int r = 0; r < 4; ++r) {
                const int rowi = wr * 32 + m * 16 + (lane >> 4) * 4 + r;
                pt[rowi * 64 + col] = acc[m][n][r];
            }
        }
}

// ---------------- Kernel C: combine K-halves + fused loss (handles mirror via symmetry) ----------------
__global__ __launch_bounds__(256) void combine_loss(const float* __restrict__ pg,
                                                    const float* __restrict__ T,
                                                    float* __restrict__ partials) {
    __shared__ float Gs[64][65];
    __shared__ float red[4];

    const int t = threadIdx.x;
    const int lane = t & 63;
    const int wid = t >> 6;
    const int bid = blockIdx.x;           // 0..319
    const int b = bid / NTILE, tile = bid % NTILE;
    const int ti = c_TI[tile], tj = c_TJ[tile];
    const bool diag = (ti == tj);
    const float invNorm = 1.0f / 33554432.0f;

    const float* p0 = pg + (size_t)bid * 2 * 4096;
    const float* p1 = p0 + 4096;
    const float* Tb = T + (size_t)b * (NCHAN * NCHAN);

    float s = 0.f;
#pragma unroll
    for (int j = 0; j < 16; ++j) {
        const int e = j * 256 + t, r = e >> 6, c = e & 63;
        const float G = (p0[e] + p1[e]) * invNorm;
        const float d = Tb[(ti * 64 + r) * NCHAN + tj * 64 + c] - G;
        s += d * d;
        if (!diag) Gs[r][c] = G;
    }
    if (!diag) {
        __syncthreads();
#pragma unroll
        for (int j = 0; j < 16; ++j) {
            const int e = j * 256 + t, r = e >> 6, c = e & 63;
            const float d = Tb[(tj * 64 + r) * NCHAN + ti * 64 + c] - Gs[c][r];
            s += d * d;
        }
    }
#pragma unroll
    for (int dd = 32; dd >= 1; dd >>= 1) s += __shfl_down(s, dd);
    if (lane == 0) red[wid] = s;
    __syncthreads();
    if (t == 0) partials[bid] = red[0] + red[1] + red[2] + red[3];
}

// ---------------- Kernel D: deterministic final reduction over 320 partials ----------------
__global__ __launch_bounds__(256) void final_reduce(const float* __restrict__ partials,
                                                    float* __restrict__ out) {
    __shared__ float red[4];
    const int t = threadIdx.x;
    const int lane = t & 63;
    const int wid = t >> 6;
    float s = partials[t] + ((t < 64) ? partials[256 + t] : 0.0f);
#pragma unroll
    for (int dd = 32; dd >= 1; dd >>= 1) s += __shfl_down(s, dd);
    if (lane == 0) red[wid] = s;
    __syncthreads();
    if (t == 0) out[0] = (red[0] + red[1] + red[2] + red[3]) * (1.0e9f / 2097152.0f);
}

extern "C" void kernel_launch(void* const* d_in, const int* in_sizes, int n_in,
                              void* d_out, int out_size, void* d_ws, size_t ws_size,
                              hipStream_t stream) {
    const float* x  = (const float*)d_in[0];           // (32,256,64,64) fp32
    const float* tg = (const float*)d_in[1];           // (32,256,256) fp32
    float* out = (float*)d_out;

    // ws layout: [0,4KiB) partials (320 f32); [4KiB, 4KiB+10.5MiB) partial-G; then F (64 MiB)
    float* partials = (float*)d_ws;
    float* pg = (float*)((char*)d_ws + 4096);
    u16* F = (u16*)((char*)d_ws + 4096 + (size_t)NBATCH * NTILE * 2 * 4096 * 4);

    topk_sparsify<<<NBATCH * NCHAN, 256, 0, stream>>>(x, F);
    gram_partial<<<NBATCH * NTILE * 2, 256, 0, stream>>>(F, pg);
    combine_loss<<<NBATCH * NTILE, 256, 0, stream>>>(pg, tg, partials);
    final_reduce<<<1, 256, 0, stream>>>(partials, out);
}